// Round 1
// baseline (94.587 us; speedup 1.0000x reference)
//
#include <hip/hip_runtime.h>
#include <hip/hip_bf16.h>

typedef __attribute__((ext_vector_type(8))) short bf16x8;
typedef __attribute__((ext_vector_type(4))) short bf16x4;
typedef __attribute__((ext_vector_type(4))) float f32x4;

#define SLEN 2048
#define DDIM 64
#define NHEADS 16
#define KEPS 1e-6f

// round-to-nearest-even fp32 -> bf16 (inputs are finite normals; no NaN path needed)
__device__ __forceinline__ short f2bf(float x) {
    unsigned u = __float_as_uint(x);
    unsigned r = (u + 0x7FFFu + ((u >> 16) & 1u)) >> 16;
    return (short)r;
}

__device__ __forceinline__ f32x4 mfma16x16x32bf16(bf16x8 a, bf16x8 b, f32x4 c) {
#if __has_builtin(__builtin_amdgcn_mfma_f32_16x16x32_bf16)
    return __builtin_amdgcn_mfma_f32_16x16x32_bf16(a, b, c, 0, 0, 0);
#else
    asm("v_mfma_f32_16x16x32_bf16 %0, %1, %2, %0" : "+v"(c) : "v"(a), "v"(b));
    return c;
#endif
}

__device__ __forceinline__ f32x4 mfma16x16x16bf16(bf16x4 a, bf16x4 b, f32x4 c) {
#if __has_builtin(__builtin_amdgcn_mfma_f32_16x16x16bf16_1k)
    return __builtin_amdgcn_mfma_f32_16x16x16bf16_1k(a, b, c, 0, 0, 0);
#else
    asm("v_mfma_f32_16x16x16_bf16 %0, %1, %2, %0" : "+v"(c) : "v"(a), "v"(b));
    return c;
#endif
}

// Rebased linear attention, causal, z = rowsum(s^2) normalization.
// Grid: 512 blocks x 256 threads. Each wave owns one 16-row Q tile.
// Block covers 64 q-rows (group g); blocks 256..511 take mirrored g for load balance.
__global__ void __launch_bounds__(256) rebased_attn_kernel(
    const float* __restrict__ Q, const float* __restrict__ K,
    const float* __restrict__ V, float* __restrict__ O)
{
    // K tile: [16 rows][64 d] bf16, row stride 72 shorts (pad: 2-way max bank alias = free)
    __shared__ __align__(16) short Klds[16 * 72];
    // V^T tile: [64 d][16 j] bf16, row stride 20 shorts (pad: conflict-free b64 reads)
    __shared__ __align__(16) short VTlds[64 * 20];

    const int b    = blockIdx.x;
    const int half = b >> 8;          // 0 or 1
    const int r8   = b & 255;
    const int h    = (half << 3) | (r8 >> 5);               // head 0..15
    const int g    = half ? (31 - (r8 & 31)) : (r8 & 31);   // 64-row group 0..31

    const int tid  = threadIdx.x;
    const int w    = tid >> 6;        // wave 0..3
    const int lane = tid & 63;
    const int l15  = lane & 15;
    const int lg   = lane >> 4;       // lane group 0..3

    const int qt = 4 * g + w;         // this wave's q-tile index (16 rows)
    const int q0 = qt * 16;

    const float* __restrict__ Qh = Q + (size_t)h * SLEN * DDIM;
    const float* __restrict__ Kh = K + (size_t)h * SLEN * DDIM;
    const float* __restrict__ Vh = V + (size_t)h * SLEN * DDIM;
    float* __restrict__ Oh = O + (size_t)h * SLEN * DDIM;

    // ---- Q fragments (held for whole kernel) ----
    // B-frag of mfma_16x16x32: lane holds Q[q0 + (l&15)][32*f + (l>>4)*8 + t], t=0..7
    bf16x8 qf[2];
#pragma unroll
    for (int f = 0; f < 2; ++f) {
        const float* src = Qh + (size_t)(q0 + l15) * DDIM + 32 * f + lg * 8;
        float4 a = *reinterpret_cast<const float4*>(src);
        float4 c = *reinterpret_cast<const float4*>(src + 4);
        bf16x8 v;
        v[0] = f2bf(a.x); v[1] = f2bf(a.y); v[2] = f2bf(a.z); v[3] = f2bf(a.w);
        v[4] = f2bf(c.x); v[5] = f2bf(c.y); v[6] = f2bf(c.z); v[7] = f2bf(c.w);
        qf[f] = v;
    }

    f32x4 oacc[4];
#pragma unroll
    for (int nb = 0; nb < 4; ++nb) oacc[nb] = (f32x4){0.f, 0.f, 0.f, 0.f};
    float zacc = 0.f;

    const int ktmax = 4 * g + 3;      // block stages up to the last wave's diagonal
    const int srow  = tid >> 4;       // staging: row 0..15
    const int scol  = (tid & 15) * 4; // staging: col 0,4,...,60

    for (int kt = 0; kt <= ktmax; ++kt) {
        const int k0 = kt * 16;

        // ---- stage K (row-major bf16) and V^T (transposed bf16) ----
        {
            const float4 kv4 = *reinterpret_cast<const float4*>(Kh + (size_t)(k0 + srow) * DDIM + scol);
            const float4 vv4 = *reinterpret_cast<const float4*>(Vh + (size_t)(k0 + srow) * DDIM + scol);
            bf16x4 kk;
            kk[0] = f2bf(kv4.x); kk[1] = f2bf(kv4.y); kk[2] = f2bf(kv4.z); kk[3] = f2bf(kv4.w);
            *reinterpret_cast<bf16x4*>(&Klds[srow * 72 + scol]) = kk;
            VTlds[(scol + 0) * 20 + srow] = f2bf(vv4.x);
            VTlds[(scol + 1) * 20 + srow] = f2bf(vv4.y);
            VTlds[(scol + 2) * 20 + srow] = f2bf(vv4.z);
            VTlds[(scol + 3) * 20 + srow] = f2bf(vv4.w);
        }
        __syncthreads();

        if (kt <= qt) {
            // ---- S^T = K_tile . Q_tile^T  (m=j, n=i, k=d; two K=32 steps) ----
            bf16x8 kf0 = *reinterpret_cast<const bf16x8*>(&Klds[l15 * 72 + 0  + lg * 8]);
            bf16x8 kf1 = *reinterpret_cast<const bf16x8*>(&Klds[l15 * 72 + 32 + lg * 8]);
            f32x4 sacc = (f32x4){0.f, 0.f, 0.f, 0.f};
            sacc = mfma16x16x32bf16(kf0, qf[0], sacc);
            sacc = mfma16x16x32bf16(kf1, qf[1], sacc);

            // lane holds S^T[j=(l>>4)*4+r][i=l&15]
            const float scale = 0.125f;  // D^-0.5
            float p[4];
#pragma unroll
            for (int rr = 0; rr < 4; ++rr) {
                float s  = sacc[rr] * scale;
                float pp = s * s;
                if (kt == qt) {
                    int j = k0 + lg * 4 + rr;
                    int i = q0 + l15;
                    if (j > i) pp = 0.f;   // causal
                }
                p[rr] = pp;
                zacc += pp;
            }

            // ---- PV: A-frag of mfma_16x16x16 is exactly our register layout ----
            bf16x4 pf;
            pf[0] = f2bf(p[0]); pf[1] = f2bf(p[1]); pf[2] = f2bf(p[2]); pf[3] = f2bf(p[3]);
#pragma unroll
            for (int nb = 0; nb < 4; ++nb) {
                // B-frag: V[k0 + (l>>4)*4 + t][16*nb + (l&15)] = VT[16*nb + l15][lg*4 + t]
                bf16x4 vf = *reinterpret_cast<const bf16x4*>(&VTlds[(nb * 16 + l15) * 20 + lg * 4]);
                oacc[nb] = mfma16x16x16bf16(pf, vf, oacc[nb]);
            }
        }
        __syncthreads();
    }

    // ---- z reduction: sum over lane groups (same l&15) ----
    float z = zacc;
    z += __shfl_xor(z, 16);
    z += __shfl_xor(z, 32);
    // every lane now has z for row i = l&15

    // ---- epilogue: O[i][d] with i=(l>>4)*4+r, d=16*nb+(l&15) ----
#pragma unroll
    for (int rr = 0; rr < 4; ++rr) {
        float zi  = __shfl(z, lg * 4 + rr);
        float inv = 1.f / (zi + KEPS);
        int row   = q0 + lg * 4 + rr;
#pragma unroll
        for (int nb = 0; nb < 4; ++nb) {
            Oh[(size_t)row * DDIM + nb * 16 + l15] = oacc[nb][rr] * inv;
        }
    }
}

extern "C" void kernel_launch(void* const* d_in, const int* in_sizes, int n_in,
                              void* d_out, int out_size, void* d_ws, size_t ws_size,
                              hipStream_t stream) {
    const float* q = (const float*)d_in[0];
    const float* k = (const float*)d_in[1];
    const float* v = (const float*)d_in[2];
    float* o = (float*)d_out;
    hipLaunchKernelGGL(rebased_attn_kernel, dim3(512), dim3(256), 0, stream, q, k, v, o);
}

// Round 2
// 42.368 us; speedup vs baseline: 2.2325x; 2.2325x over previous
//
#include <hip/hip_runtime.h>
#include <hip/hip_bf16.h>

typedef __attribute__((ext_vector_type(8))) short bf16x8;
typedef __attribute__((ext_vector_type(4))) short bf16x4;
typedef __attribute__((ext_vector_type(4))) float f32x4;

#define SLEN 2048
#define DDIM 64
#define KEPS 1e-6f
#define KSTR 76   // K LDS row stride in shorts (152 B: <=2-way bank alias on b64 ops)
#define VSTR 76   // V^T LDS row stride in shorts

// fp32 -> bf16 RNE (used only for the once-per-kernel Q fragment)
__device__ __forceinline__ short f2bf(float x) {
    unsigned u = __float_as_uint(x);
    unsigned r = (u + 0x7FFFu + ((u >> 16) & 1u)) >> 16;
    return (short)r;
}

// packed fp32x2 -> bf16x2 RNE, single VALU op
__device__ __forceinline__ unsigned cvtpk(float lo, float hi) {
    unsigned r;
    asm("v_cvt_pk_bf16_f32 %0, %1, %2" : "=v"(r) : "v"(lo), "v"(hi));
    return r;
}

__device__ __forceinline__ f32x4 mfma16x16x32bf16(bf16x8 a, bf16x8 b, f32x4 c) {
#if __has_builtin(__builtin_amdgcn_mfma_f32_16x16x32_bf16)
    return __builtin_amdgcn_mfma_f32_16x16x32_bf16(a, b, c, 0, 0, 0);
#else
    asm("v_mfma_f32_16x16x32_bf16 %0, %1, %2, %0" : "+v"(c) : "v"(a), "v"(b));
    return c;
#endif
}

__device__ __forceinline__ f32x4 mfma16x16x16bf16(bf16x4 a, bf16x4 b, f32x4 c) {
#if __has_builtin(__builtin_amdgcn_mfma_f32_16x16x16bf16_1k)
    return __builtin_amdgcn_mfma_f32_16x16x16bf16_1k(a, b, c, 0, 0, 0);
#else
    asm("v_mfma_f32_16x16x16_bf16 %0, %1, %2, %0" : "+v"(c) : "v"(a), "v"(b));
    return c;
#endif
}

// Rebased linear attention, causal, z = rowsum(s^2) normalization.
// Grid: 512 blocks x 256 threads. Block = 64 q-rows (4 waves x 16), KV tile = 64 rows,
// double-buffered LDS, one barrier per tile, prefetch-to-registers overlaps MFMA.
__global__ void __launch_bounds__(256) rebased_attn_kernel(
    const float* __restrict__ Q, const float* __restrict__ K,
    const float* __restrict__ V, float* __restrict__ O)
{
    __shared__ __align__(16) short Klds[2][64 * KSTR];   // [kv row][d] bf16
    __shared__ __align__(16) short VTlds[2][64 * VSTR];  // [d][kv row] bf16

    const int b    = blockIdx.x;
    const int half = b >> 8;
    const int r8   = b & 255;
    const int h    = (half << 3) | (r8 >> 5);               // head 0..15
    const int g    = half ? (31 - (r8 & 31)) : (r8 & 31);   // 64-row q group, mirrored

    const int tid  = threadIdx.x;
    const int w    = tid >> 6;
    const int lane = tid & 63;
    const int l15  = lane & 15;
    const int lg   = lane >> 4;

    const int q0 = g * 64 + w * 16;     // this wave's 16 q-rows

    const float* __restrict__ Qh = Q + (size_t)h * SLEN * DDIM;
    const float* __restrict__ Kh = K + (size_t)h * SLEN * DDIM;
    const float* __restrict__ Vh = V + (size_t)h * SLEN * DDIM;
    float* __restrict__ Oh = O + (size_t)h * SLEN * DDIM;

    // ---- Q fragments (whole kernel): B-frag of 16x16x32, lane holds Q[q0+l15][32f+lg*8+t]
    bf16x8 qf[2];
#pragma unroll
    for (int f = 0; f < 2; ++f) {
        const float* src = Qh + (size_t)(q0 + l15) * DDIM + 32 * f + lg * 8;
        float4 a = *reinterpret_cast<const float4*>(src);
        float4 c = *reinterpret_cast<const float4*>(src + 4);
        bf16x8 v;
        v[0] = f2bf(a.x); v[1] = f2bf(a.y); v[2] = f2bf(a.z); v[3] = f2bf(a.w);
        v[4] = f2bf(c.x); v[5] = f2bf(c.y); v[6] = f2bf(c.z); v[7] = f2bf(c.w);
        qf[f] = v;
    }

    f32x4 oacc[4];
#pragma unroll
    for (int nb = 0; nb < 4; ++nb) oacc[nb] = (f32x4){0.f, 0.f, 0.f, 0.f};
    float zacc = 0.f;

    // staging thread mappings
    const int ksr = tid >> 4;          // K: sub-row 0..15 (row = q*16 + ksr)
    const int ksc = (tid & 15) * 4;    // K/V: col 0,4,...,60
    const int vj0 = (tid >> 4) * 4;    // V: row group 0,4,...,60

    // ---- stage tile 0 into buf 0 ----
    {
        float4 kreg[4], vreg[4];
#pragma unroll
        for (int q = 0; q < 4; ++q)
            kreg[q] = *reinterpret_cast<const float4*>(Kh + (size_t)(q * 16 + ksr) * DDIM + ksc);
#pragma unroll
        for (int r = 0; r < 4; ++r)
            vreg[r] = *reinterpret_cast<const float4*>(Vh + (size_t)(vj0 + r) * DDIM + ksc);
#pragma unroll
        for (int q = 0; q < 4; ++q) {
            uint2 p = make_uint2(cvtpk(kreg[q].x, kreg[q].y), cvtpk(kreg[q].z, kreg[q].w));
            *reinterpret_cast<uint2*>(&Klds[0][(q * 16 + ksr) * KSTR + ksc]) = p;
        }
#pragma unroll
        for (int c = 0; c < 4; ++c) {
            uint2 p = make_uint2(
                cvtpk(((const float*)&vreg[0])[c], ((const float*)&vreg[1])[c]),
                cvtpk(((const float*)&vreg[2])[c], ((const float*)&vreg[3])[c]));
            *reinterpret_cast<uint2*>(&VTlds[0][(ksc + c) * VSTR + vj0]) = p;
        }
    }
    __syncthreads();

    for (int kt = 0; kt <= g; ++kt) {
        const int  cur     = kt & 1;
        const bool hasNext = (kt < g);

        // ---- issue next-tile global loads early (overlap with MFMA below) ----
        float4 kreg[4], vreg[4];
        if (hasNext) {
            const int k0n = (kt + 1) * 64;
#pragma unroll
            for (int q = 0; q < 4; ++q)
                kreg[q] = *reinterpret_cast<const float4*>(Kh + (size_t)(k0n + q * 16 + ksr) * DDIM + ksc);
#pragma unroll
            for (int r = 0; r < 4; ++r)
                vreg[r] = *reinterpret_cast<const float4*>(Vh + (size_t)(k0n + vj0 + r) * DDIM + ksc);
        }

        // ---- compute on buf[cur] ----
        const int nsub = hasNext ? 4 : (w + 1);  // last tile: wave w handles subtiles 0..w
        for (int js = 0; js < nsub; ++js) {
            const short* kb = &Klds[cur][(js * 16 + l15) * KSTR + lg * 8];
            bf16x4 k00 = *reinterpret_cast<const bf16x4*>(kb);
            bf16x4 k01 = *reinterpret_cast<const bf16x4*>(kb + 4);
            bf16x4 k10 = *reinterpret_cast<const bf16x4*>(kb + 32);
            bf16x4 k11 = *reinterpret_cast<const bf16x4*>(kb + 36);
            bf16x8 kf0 = __builtin_shufflevector(k00, k01, 0, 1, 2, 3, 4, 5, 6, 7);
            bf16x8 kf1 = __builtin_shufflevector(k10, k11, 0, 1, 2, 3, 4, 5, 6, 7);

            f32x4 sacc = (f32x4){0.f, 0.f, 0.f, 0.f};
            sacc = mfma16x16x32bf16(kf0, qf[0], sacc);
            sacc = mfma16x16x32bf16(kf1, qf[1], sacc);

            // lane holds S^T[j = js*16 + lg*4 + rr][i = l15]; p = (s/8)^2 = s^2/64
            float p[4];
#pragma unroll
            for (int rr = 0; rr < 4; ++rr)
                p[rr] = sacc[rr] * sacc[rr] * 0.015625f;

            if (!hasNext && js == w) {  // diagonal subtile: mask j_local > i_local
#pragma unroll
                for (int rr = 0; rr < 4; ++rr)
                    if (lg * 4 + rr > l15) p[rr] = 0.f;
            }
            zacc += (p[0] + p[1]) + (p[2] + p[3]);

            // PV: A-frag (P) is exactly our register layout; B-frag from V^T LDS
            unsigned plo = cvtpk(p[0], p[1]);
            unsigned phi = cvtpk(p[2], p[3]);
            uint2 pu = make_uint2(plo, phi);
            bf16x4 pfr = *reinterpret_cast<bf16x4*>(&pu);
#pragma unroll
            for (int nb = 0; nb < 4; ++nb) {
                bf16x4 vf = *reinterpret_cast<const bf16x4*>(
                    &VTlds[cur][(nb * 16 + l15) * VSTR + js * 16 + lg * 4]);
                oacc[nb] = mfma16x16x16bf16(pfr, vf, oacc[nb]);
            }
        }

        // ---- convert + write next tile into buf[cur^1] ----
        if (hasNext) {
            const int nxt = cur ^ 1;
#pragma unroll
            for (int q = 0; q < 4; ++q) {
                uint2 p = make_uint2(cvtpk(kreg[q].x, kreg[q].y), cvtpk(kreg[q].z, kreg[q].w));
                *reinterpret_cast<uint2*>(&Klds[nxt][(q * 16 + ksr) * KSTR + ksc]) = p;
            }
#pragma unroll
            for (int c = 0; c < 4; ++c) {
                uint2 p = make_uint2(
                    cvtpk(((const float*)&vreg[0])[c], ((const float*)&vreg[1])[c]),
                    cvtpk(((const float*)&vreg[2])[c], ((const float*)&vreg[3])[c]));
                *reinterpret_cast<uint2*>(&VTlds[nxt][(ksc + c) * VSTR + vj0]) = p;
            }
        }
        __syncthreads();
    }

    // ---- z reduction: sum over lane groups (same l15) ----
    float z = zacc;
    z += __shfl_xor(z, 16);
    z += __shfl_xor(z, 32);

    // ---- epilogue: O[i][d], i = q0 + lg*4 + rr, d = nb*16 + l15 ----
#pragma unroll
    for (int rr = 0; rr < 4; ++rr) {
        float zi  = __shfl(z, lg * 4 + rr);
        float inv = 1.f / (zi + KEPS);
        int row   = q0 + lg * 4 + rr;
#pragma unroll
        for (int nb = 0; nb < 4; ++nb) {
            Oh[(size_t)row * DDIM + nb * 16 + l15] = oacc[nb][rr] * inv;
        }
    }
}

extern "C" void kernel_launch(void* const* d_in, const int* in_sizes, int n_in,
                              void* d_out, int out_size, void* d_ws, size_t ws_size,
                              hipStream_t stream) {
    const float* q = (const float*)d_in[0];
    const float* k = (const float*)d_in[1];
    const float* v = (const float*)d_in[2];
    float* o = (float*)d_out;
    hipLaunchKernelGGL(rebased_attn_kernel, dim3(512), dim3(256), 0, stream, q, k, v, o);
}

// Round 3
// 34.987 us; speedup vs baseline: 2.7035x; 1.2109x over previous
//
#include <hip/hip_runtime.h>
#include <hip/hip_bf16.h>

typedef __attribute__((ext_vector_type(8))) short bf16x8;
typedef __attribute__((ext_vector_type(4))) short bf16x4;
typedef __attribute__((ext_vector_type(4))) float f32x4;

#define SLEN 2048
#define DDIM 64
#define KEPS 1e-6f
#define KSTR 76   // LDS row stride in shorts (152 B)
#define VSTR 76

// fp32 -> bf16 RNE (Q fragment only)
__device__ __forceinline__ short f2bf(float x) {
    unsigned u = __float_as_uint(x);
    unsigned r = (u + 0x7FFFu + ((u >> 16) & 1u)) >> 16;
    return (short)r;
}

// packed fp32x2 -> bf16x2, single VALU op
__device__ __forceinline__ unsigned cvtpk(float lo, float hi) {
    unsigned r;
    asm("v_cvt_pk_bf16_f32 %0, %1, %2" : "=v"(r) : "v"(lo), "v"(hi));
    return r;
}

__device__ __forceinline__ f32x4 mfma16x16x32bf16(bf16x8 a, bf16x8 b, f32x4 c) {
#if __has_builtin(__builtin_amdgcn_mfma_f32_16x16x32_bf16)
    return __builtin_amdgcn_mfma_f32_16x16x32_bf16(a, b, c, 0, 0, 0);
#else
    asm("v_mfma_f32_16x16x32_bf16 %0, %1, %2, %0" : "+v"(c) : "v"(a), "v"(b));
    return c;
#endif
}

__device__ __forceinline__ f32x4 mfma16x16x16bf16(bf16x4 a, bf16x4 b, f32x4 c) {
#if __has_builtin(__builtin_amdgcn_mfma_f32_16x16x16bf16_1k)
    return __builtin_amdgcn_mfma_f32_16x16x16bf16_1k(a, b, c, 0, 0, 0);
#else
    asm("v_mfma_f32_16x16x16_bf16 %0, %1, %2, %0" : "+v"(c) : "v"(a), "v"(b));
    return c;
#endif
}

// Rebased linear attention, causal, z = rowsum(s^2).
// Grid 512 x 512 threads. Block = 64 q-rows, 8 waves:
//   wave w: q-tile (w&3), KV-parity (w>>2). Parity p computes KV tiles kt = 2t+p.
// Per super-iteration: stage TWO 64-row KV tiles (one per parity), double-buffered.
// Parity partials combined via LDS at the end. Mirrored g for per-CU balance.
__global__ void __launch_bounds__(512, 4) rebased_attn_kernel(
    const float* __restrict__ Q, const float* __restrict__ K,
    const float* __restrict__ V, float* __restrict__ O)
{
    __shared__ __align__(16) short Klds[2][2][64 * KSTR];   // [dbuf][parity][row*KSTR+d]
    __shared__ __align__(16) short VTlds[2][2][64 * VSTR];  // [dbuf][parity][d*VSTR+row]

    const int b    = blockIdx.x;
    const int half = b >> 8;
    const int r8   = b & 255;
    const int h    = (half << 3) | (r8 >> 5);               // head 0..15
    const int g    = half ? (31 - (r8 & 31)) : (r8 & 31);   // 64-row q group, mirrored

    const int tid  = threadIdx.x;
    const int w    = tid >> 6;        // wave 0..7
    const int lane = tid & 63;
    const int l15  = lane & 15;
    const int lg   = lane >> 4;
    const int qt   = w & 3;           // q-tile within group
    const int p    = w >> 2;          // KV parity

    const int q0 = g * 64 + qt * 16;

    const float* __restrict__ Qh = Q + (size_t)h * SLEN * DDIM;
    const float* __restrict__ Kh = K + (size_t)h * SLEN * DDIM;
    const float* __restrict__ Vh = V + (size_t)h * SLEN * DDIM;
    float* __restrict__ Oh = O + (size_t)h * SLEN * DDIM;

    // ---- Q fragments: B-frag of 16x16x32, lane holds Q[q0+l15][32f+lg*8+t]
    bf16x8 qf[2];
#pragma unroll
    for (int f = 0; f < 2; ++f) {
        const float* src = Qh + (size_t)(q0 + l15) * DDIM + 32 * f + lg * 8;
        float4 a = *reinterpret_cast<const float4*>(src);
        float4 c = *reinterpret_cast<const float4*>(src + 4);
        bf16x8 v;
        v[0] = f2bf(a.x); v[1] = f2bf(a.y); v[2] = f2bf(a.z); v[3] = f2bf(a.w);
        v[4] = f2bf(c.x); v[5] = f2bf(c.y); v[6] = f2bf(c.z); v[7] = f2bf(c.w);
        qf[f] = v;
    }

    f32x4 oacc[4];
#pragma unroll
    for (int nb = 0; nb < 4; ++nb) oacc[nb] = (f32x4){0.f, 0.f, 0.f, 0.f};
    float zacc = 0.f;

    // staging mapping: threads 0..255 stage parity-0 tile, 256..511 parity-1 tile
    const int pt   = tid >> 8;
    const int t255 = tid & 255;
    const int ksr  = t255 >> 4;         // K sub-row 0..15
    const int ksc  = (t255 & 15) * 4;   // col 0,4,...,60
    const int vj0  = (t255 >> 4) * 4;   // V row group 0,4,...,60

    const int T = (g + 2) >> 1;         // ceil((g+1)/2) super-iterations

    float4 kreg[4], vreg[4];
    // ---- prologue: stage pair 0 (tiles 0 and 1) into buf 0 ----
    {
        const int base = pt * 64;
#pragma unroll
        for (int q = 0; q < 4; ++q)
            kreg[q] = *reinterpret_cast<const float4*>(Kh + (size_t)(base + q * 16 + ksr) * DDIM + ksc);
#pragma unroll
        for (int r = 0; r < 4; ++r)
            vreg[r] = *reinterpret_cast<const float4*>(Vh + (size_t)(base + vj0 + r) * DDIM + ksc);
#pragma unroll
        for (int q = 0; q < 4; ++q) {
            uint2 pk = make_uint2(cvtpk(kreg[q].x, kreg[q].y), cvtpk(kreg[q].z, kreg[q].w));
            *reinterpret_cast<uint2*>(&Klds[0][pt][(q * 16 + ksr) * KSTR + ksc]) = pk;
        }
#pragma unroll
        for (int c = 0; c < 4; ++c) {
            uint2 pk = make_uint2(
                cvtpk(((const float*)&vreg[0])[c], ((const float*)&vreg[1])[c]),
                cvtpk(((const float*)&vreg[2])[c], ((const float*)&vreg[3])[c]));
            *reinterpret_cast<uint2*>(&VTlds[0][pt][(ksc + c) * VSTR + vj0]) = pk;
        }
    }
    __syncthreads();

    for (int t = 0; t < T; ++t) {
        const int  cur     = t & 1;
        const bool hasNext = (t < T - 1);

        // ---- issue next-pair global loads early (overlap with MFMA) ----
        if (hasNext) {
            const int base = (2 * (t + 1) + pt) * 64;
#pragma unroll
            for (int q = 0; q < 4; ++q)
                kreg[q] = *reinterpret_cast<const float4*>(Kh + (size_t)(base + q * 16 + ksr) * DDIM + ksc);
#pragma unroll
            for (int r = 0; r < 4; ++r)
                vreg[r] = *reinterpret_cast<const float4*>(Vh + (size_t)(base + vj0 + r) * DDIM + ksc);
        }

        // ---- compute on buf[cur], my parity's tile ----
        const int kt = 2 * t + p;
        if (kt <= g) {
            const bool diag = (kt == g);
            const int  nsub = diag ? (qt + 1) : 4;
            __builtin_amdgcn_s_setprio(1);
            for (int js = 0; js < nsub; ++js) {
                const short* kb = &Klds[cur][p][(js * 16 + l15) * KSTR + lg * 8];
                bf16x4 k00 = *reinterpret_cast<const bf16x4*>(kb);
                bf16x4 k01 = *reinterpret_cast<const bf16x4*>(kb + 4);
                bf16x4 k10 = *reinterpret_cast<const bf16x4*>(kb + 32);
                bf16x4 k11 = *reinterpret_cast<const bf16x4*>(kb + 36);
                bf16x8 kf0 = __builtin_shufflevector(k00, k01, 0, 1, 2, 3, 4, 5, 6, 7);
                bf16x8 kf1 = __builtin_shufflevector(k10, k11, 0, 1, 2, 3, 4, 5, 6, 7);

                f32x4 sacc = (f32x4){0.f, 0.f, 0.f, 0.f};
                sacc = mfma16x16x32bf16(kf0, qf[0], sacc);
                sacc = mfma16x16x32bf16(kf1, qf[1], sacc);

                // lane holds S^T[j = js*16 + lg*4 + rr][i = l15]; p = (s/8)^2
                float pv[4];
#pragma unroll
                for (int rr = 0; rr < 4; ++rr)
                    pv[rr] = sacc[rr] * sacc[rr] * 0.015625f;
                if (diag && js == qt) {
#pragma unroll
                    for (int rr = 0; rr < 4; ++rr)
                        if (lg * 4 + rr > l15) pv[rr] = 0.f;
                }
                zacc += (pv[0] + pv[1]) + (pv[2] + pv[3]);

                uint2 pu = make_uint2(cvtpk(pv[0], pv[1]), cvtpk(pv[2], pv[3]));
                bf16x4 pfr = *reinterpret_cast<bf16x4*>(&pu);
#pragma unroll
                for (int nb = 0; nb < 4; ++nb) {
                    bf16x4 vf = *reinterpret_cast<const bf16x4*>(
                        &VTlds[cur][p][(nb * 16 + l15) * VSTR + js * 16 + lg * 4]);
                    oacc[nb] = mfma16x16x16bf16(pfr, vf, oacc[nb]);
                }
            }
            __builtin_amdgcn_s_setprio(0);
        }

        // ---- convert + write next pair into buf[cur^1] ----
        if (hasNext) {
            const int nxt = cur ^ 1;
#pragma unroll
            for (int q = 0; q < 4; ++q) {
                uint2 pk = make_uint2(cvtpk(kreg[q].x, kreg[q].y), cvtpk(kreg[q].z, kreg[q].w));
                *reinterpret_cast<uint2*>(&Klds[nxt][pt][(q * 16 + ksr) * KSTR + ksc]) = pk;
            }
#pragma unroll
            for (int c = 0; c < 4; ++c) {
                uint2 pk = make_uint2(
                    cvtpk(((const float*)&vreg[0])[c], ((const float*)&vreg[1])[c]),
                    cvtpk(((const float*)&vreg[2])[c], ((const float*)&vreg[3])[c]));
                *reinterpret_cast<uint2*>(&VTlds[nxt][pt][(ksc + c) * VSTR + vj0]) = pk;
            }
        }
        __syncthreads();
    }

    // ---- combine parity partials via LDS (stride 17 floats: conflict-free) ----
    float* red = (float*)&Klds[0][0][0];
    if (p == 1) {
        const int idx = (qt * 64 + lane) * 17;
#pragma unroll
        for (int nb = 0; nb < 4; ++nb)
#pragma unroll
            for (int rr = 0; rr < 4; ++rr)
                red[idx + nb * 4 + rr] = oacc[nb][rr];
        red[idx + 16] = zacc;
    }
    __syncthreads();
    if (p == 0) {
        const int idx = (qt * 64 + lane) * 17;
#pragma unroll
        for (int nb = 0; nb < 4; ++nb)
#pragma unroll
            for (int rr = 0; rr < 4; ++rr)
                oacc[nb][rr] += red[idx + nb * 4 + rr];
        zacc += red[idx + 16];

        float z = zacc;
        z += __shfl_xor(z, 16);
        z += __shfl_xor(z, 32);

#pragma unroll
        for (int rr = 0; rr < 4; ++rr) {
            float zi  = __shfl(z, lg * 4 + rr);
            float inv = 1.f / (zi + KEPS);
            int row   = q0 + lg * 4 + rr;
#pragma unroll
            for (int nb = 0; nb < 4; ++nb) {
                Oh[(size_t)row * DDIM + nb * 16 + l15] = oacc[nb][rr] * inv;
            }
        }
    }
}

extern "C" void kernel_launch(void* const* d_in, const int* in_sizes, int n_in,
                              void* d_out, int out_size, void* d_ws, size_t ws_size,
                              hipStream_t stream) {
    const float* q = (const float*)d_in[0];
    const float* k = (const float*)d_in[1];
    const float* v = (const float*)d_in[2];
    float* o = (float*)d_out;
    hipLaunchKernelGGL(rebased_attn_kernel, dim3(512), dim3(512), 0, stream, q, k, v, o);
}